// Round 9
// baseline (208.389 us; speedup 1.0000x reference)
//
#include <hip/hip_runtime.h>

#define D 1024      // in_features
#define E 64        // num experts
#define TPB 256     // threads per block (4 waves)
#define TOKS 64     // tokens per block (16 per wave)
#define NCH 16      // chunks of 64 k (2 MFMA k-steps) -> 16 barrier phases
#define WCB 16384   // W bytes per chunk (2 ks x 8 records x 1KB)
#define APITCH 68   // A LDS row pitch in floats (64 + 4 pad -> 2-way banks only)

typedef __attribute__((ext_vector_type(8))) short bf16x8;
typedef __attribute__((ext_vector_type(8))) unsigned short u16x8;
typedef __attribute__((ext_vector_type(4))) float f32x4;
typedef __attribute__((ext_vector_type(4))) unsigned int u32x4;

__device__ __forceinline__ unsigned short bf16_rne(float f) {
    unsigned u = __builtin_bit_cast(unsigned, f);
    u += 0x7fffu + ((u >> 16) & 1u);
    return (unsigned short)(u >> 16);
}
__device__ __forceinline__ float bf16_to_f(unsigned short h) {
    unsigned u = ((unsigned)h) << 16;
    return __builtin_bit_cast(float, u);
}
__device__ __forceinline__ unsigned cvt_pk_bf16(float a, float b) {
    // dst[15:0]=bf16_rne(a), dst[31:16]=bf16_rne(b) — bit-identical to bf16_rne
    unsigned r;
    asm("v_cvt_pk_bf16_f32 %0, %1, %2" : "=v"(r) : "v"(a), "v"(b));
    return r;
}
__device__ __forceinline__ float lo_val(unsigned p) {
    return __builtin_bit_cast(float, p << 16);
}
__device__ __forceinline__ float hi_val(unsigned p) {
    return __builtin_bit_cast(float, p & 0xffff0000u);
}

// Split 8 fp32 into bf16 hi (RNE) + bf16 lo (RNE of exact residual).
// Bitwise-identical values to the original verified split_hi_lo scheme.
__device__ __forceinline__ void split8_rne(f32x4 a, f32x4 b, bf16x8& hv, bf16x8& lv) {
    unsigned h0 = cvt_pk_bf16(a[0], a[1]);
    unsigned h1 = cvt_pk_bf16(a[2], a[3]);
    unsigned h2 = cvt_pk_bf16(b[0], b[1]);
    unsigned h3 = cvt_pk_bf16(b[2], b[3]);
    unsigned l0 = cvt_pk_bf16(a[0] - lo_val(h0), a[1] - hi_val(h0));
    unsigned l1 = cvt_pk_bf16(a[2] - lo_val(h1), a[3] - hi_val(h1));
    unsigned l2 = cvt_pk_bf16(b[0] - lo_val(h2), b[1] - hi_val(h2));
    unsigned l3 = cvt_pk_bf16(b[2] - lo_val(h3), b[3] - hi_val(h3));
    hv = __builtin_bit_cast(bf16x8, (u32x4){h0, h1, h2, h3});
    lv = __builtin_bit_cast(bf16x8, (u32x4){l0, l1, l2, l3});
}

// ---------------------------------------------------------------------------
// One-time prep (proven): W -> RNE hi/lo bf16 in MFMA B-fragment lane order.
// Record f = (ks*8 + nt*2 + hl): 64 lanes x 16B; lane (n,q) holds
// W[nt*16+n][ks*32 + q*8 + 0..7].  256 KB -> d_ws.
// ---------------------------------------------------------------------------
__global__ __launch_bounds__(256) void router_prep(
        const float* __restrict__ W, unsigned short* __restrict__ Ws) {
    int t = blockIdx.x * 256 + threadIdx.x;  // 0..8191
    int lane = t & 63;
    int nt = (t >> 6) & 3;
    int ks = t >> 8;
    int n = lane & 15, q = lane >> 4;
    const float* src = W + (size_t)(nt * 16 + n) * D + ks * 32 + q * 8;
    u16x8 hv, lv;
#pragma unroll
    for (int j = 0; j < 8; ++j) {
        float v = src[j];
        unsigned short h = bf16_rne(v);
        hv[j] = h;
        lv[j] = bf16_rne(v - bf16_to_f(h));
    }
    size_t base = ((size_t)(ks * 8 + nt * 2) * 64 + lane) * 8;
    *(u16x8*)(Ws + base)          = hv;      // hl = 0
    *(u16x8*)(Ws + base + 64 * 8) = lv;      // hl = 1
}

// ---------------------------------------------------------------------------
// Main: r8 skeleton (barrier-batched phases, pre-split W, the proven best),
// PLUS the one change never cleanly tested: A is staged into LDS with fully
// coalesced global loads (8 cache lines per wave-instruction) instead of the
// 4KB-lane-stride direct loads (~16-32 lines/instr) that every previous
// version shared.  MFMA A-fragments come from LDS (ds_read_b128, padded
// pitch -> 2-way bank aliasing only, which is free).  split8_rne runs after
// the LDS read, so logits are bitwise identical to all passing rounds.
// 16 chunks of 64 k, double-buffered, one barrier per phase, ~68 KB LDS.
// ---------------------------------------------------------------------------
__global__ __launch_bounds__(TPB) void router_main(
        const float* __restrict__ x, const unsigned short* __restrict__ Ws,
        const float* __restrict__ bias, float* __restrict__ out, int T) {
    __shared__ __align__(16) union SM {
        struct {
            unsigned char w[2][WCB];            // 32 KB staged W (dbuf)
            float a[2][TOKS][APITCH];           // 34.8 KB staged A (dbuf)
        } k;
        float ls[TOKS][E + 1];                  // epilogue logits (union reuse)
    } sm;
    __shared__ float sbias[E];

    const int tid  = threadIdx.x;
    const int lane = tid & 63;
    const int wid  = tid >> 6;
    const int n    = lane & 15;
    const int q    = lane >> 4;
    const int t0   = blockIdx.x * TOKS;
    const int arow = tid >> 4;          // staging row base 0..15
    const int acol = (tid & 15) * 4;    // staging float offset within chunk

    if (tid < E) sbias[tid] = bias[tid];

    const float* xb = x + (size_t)t0 * D + acol;
    const u32x4* gws = (const u32x4*)Ws;

    f32x4 c0 = {0.f, 0.f, 0.f, 0.f}, c1 = c0, c2 = c0, c3 = c0;

    // Named register stage batches only (rule #20).
    u32x4 W0, W1, W2, W3;               // W chunk (4 x 16B, coalesced)
    f32x4 A0, A1, A2, A3;               // A chunk (4 rows x 16B, coalesced)

#define ISSUE(c_) do {                                                \
        const u32x4* _g = gws + (size_t)(c_) * 1024 + tid;            \
        W0 = _g[0]; W1 = _g[256]; W2 = _g[512]; W3 = _g[768];         \
        const float* _x = xb + (c_) * 64;                             \
        A0 = *(const f32x4*)(_x + (size_t)(arow     ) * D);           \
        A1 = *(const f32x4*)(_x + (size_t)(arow + 16) * D);           \
        A2 = *(const f32x4*)(_x + (size_t)(arow + 32) * D);           \
        A3 = *(const f32x4*)(_x + (size_t)(arow + 48) * D);           \
    } while (0)

#define WRITE(bi_) do {                                               \
        u32x4* _l = (u32x4*)sm.k.w[bi_] + tid;                        \
        _l[0] = W0; _l[256] = W1; _l[512] = W2; _l[768] = W3;         \
        *(f32x4*)&sm.k.a[bi_][arow     ][acol] = A0;                  \
        *(f32x4*)&sm.k.a[bi_][arow + 16][acol] = A1;                  \
        *(f32x4*)&sm.k.a[bi_][arow + 32][acol] = A2;                  \
        *(f32x4*)&sm.k.a[bi_][arow + 48][acol] = A3;                  \
    } while (0)

#define MFMA __builtin_amdgcn_mfma_f32_16x16x32_bf16
// One MFMA k-step from LDS buffers; accumulation order identical to all
// passing rounds: per nt, (ah,bh),(al,bh),(ah,bl).
#define COMPSTEP(bi_, ksl_) do {                                      \
        const float* _a = &sm.k.a[bi_][wid * 16 + n][(ksl_) * 32 + q * 8]; \
        f32x4 au = *(const f32x4*)_a;                                 \
        f32x4 av = *(const f32x4*)(_a + 4);                           \
        bf16x8 ah, al;                                                \
        split8_rne(au, av, ah, al);                                   \
        const char* _p = (const char*)sm.k.w[bi_] + (ksl_) * 8192 + lane * 16; \
        {                                                             \
            bf16x8 bh = *(const bf16x8*)(_p);                         \
            bf16x8 bl = *(const bf16x8*)(_p + 1024);                  \
            c0 = MFMA(ah, bh, c0, 0, 0, 0);                           \
            c0 = MFMA(al, bh, c0, 0, 0, 0);                           \
            c0 = MFMA(ah, bl, c0, 0, 0, 0);                           \
        }                                                             \
        {                                                             \
            bf16x8 bh = *(const bf16x8*)(_p + 2048);                  \
            bf16x8 bl = *(const bf16x8*)(_p + 3072);                  \
            c1 = MFMA(ah, bh, c1, 0, 0, 0);                           \
            c1 = MFMA(al, bh, c1, 0, 0, 0);                           \
            c1 = MFMA(ah, bl, c1, 0, 0, 0);                           \
        }                                                             \
        {                                                             \
            bf16x8 bh = *(const bf16x8*)(_p + 4096);                  \
            bf16x8 bl = *(const bf16x8*)(_p + 5120);                  \
            c2 = MFMA(ah, bh, c2, 0, 0, 0);                           \
            c2 = MFMA(al, bh, c2, 0, 0, 0);                           \
            c2 = MFMA(ah, bl, c2, 0, 0, 0);                           \
        }                                                             \
        {                                                             \
            bf16x8 bh = *(const bf16x8*)(_p + 6144);                  \
            bf16x8 bl = *(const bf16x8*)(_p + 7168);                  \
            c3 = MFMA(ah, bh, c3, 0, 0, 0);                           \
            c3 = MFMA(al, bh, c3, 0, 0, 0);                           \
            c3 = MFMA(ah, bl, c3, 0, 0, 0);                           \
        }                                                             \
    } while (0)

    // ---- prologue: chunk 0 into buf0 ----
    ISSUE(0);
    WRITE(0);
    __syncthreads();

    // ---- 16 phases, one barrier each; 2x unroll keeps buffer names static ----
    for (int c = 0; c < NCH; c += 2) {
        // even chunk c: prefetch c+1 (coalesced), compute buf0, stage -> buf1
        ISSUE(c + 1);
        COMPSTEP(0, 0);
        COMPSTEP(0, 1);
        WRITE(1);
        __syncthreads();
        // odd chunk c+1: prefetch c+2 (wrap harmless), compute buf1
        ISSUE((c + 2) & (NCH - 1));
        COMPSTEP(1, 0);
        COMPSTEP(1, 1);
        WRITE(0);
        __syncthreads();
    }

    // ---- epilogue: logits (+bias) into union'd LDS, softmax + top-2 ----
    {
        const int row = wid * 16 + q * 4;
#define STORE_C(c_, nt_) do {                                         \
            int col = (nt_) * 16 + n;                                 \
            float bv = sbias[col];                                    \
            sm.ls[row + 0][col] = c_[0] + bv;                         \
            sm.ls[row + 1][col] = c_[1] + bv;                         \
            sm.ls[row + 2][col] = c_[2] + bv;                         \
            sm.ls[row + 3][col] = c_[3] + bv;                         \
        } while (0)
        STORE_C(c0, 0); STORE_C(c1, 1); STORE_C(c2, 2); STORE_C(c3, 3);
#undef STORE_C
    }
    __syncthreads();

    if (tid < TOKS) {
        float m1 = -3.4e38f, m2 = -3.4e38f;
        int i1 = 0, i2 = 0;
        for (int e = 0; e < E; ++e) {
            float v = sm.ls[tid][e];
            if (v > m1) { m2 = m1; i2 = i1; m1 = v; i1 = e; }
            else if (v > m2) { m2 = v; i2 = e; }
        }
        float Z = 0.f;
        for (int e = 0; e < E; ++e) Z += __expf(sm.ls[tid][e] - m1);
        float inv = 1.f / Z;
        int gt = t0 + tid;
        out[(size_t)gt * 2]     = inv;                  // exp(m1-m1)/Z
        out[(size_t)gt * 2 + 1] = __expf(m2 - m1) * inv;
        float* oi = out + (size_t)T * 2;
        oi[(size_t)gt * 2]     = (float)i1;             // indices as floats
        oi[(size_t)gt * 2 + 1] = (float)i2;
    }
}

extern "C" void kernel_launch(void* const* d_in, const int* in_sizes, int n_in,
                              void* d_out, int out_size, void* d_ws, size_t ws_size,
                              hipStream_t stream) {
    const float* x = (const float*)d_in[0];
    const float* W = (const float*)d_in[1];
    const float* b = (const float*)d_in[2];
    float* out = (float*)d_out;
    unsigned short* Ws = (unsigned short*)d_ws;   // needs 256 KB
    int T = in_sizes[0] / D;                      // 32768 tokens
    hipLaunchKernelGGL(router_prep, dim3(32), dim3(256), 0, stream, W, Ws);
    hipLaunchKernelGGL(router_main, dim3(T / TOKS), dim3(TPB), 0, stream,
                       x, Ws, b, out, T);
}